// Round 5
// baseline (361.266 us; speedup 1.0000x reference)
//
#include <hip/hip_runtime.h>

#define NINST 100
#define MLOG 28
#define IMG 800
#define LOGSZ (MLOG * MLOG) /* 784 */

// ws layout (32-bit words):
//  [0..99]    order (original index of n-th highest cls_prob)
//  [100..199] cls (0-based class of ordered instance)
//  [200..599] box (x0,y0,x1,y1 per ordered instance, int-truncated)
//  [600..699] msum
//  [800..899] slot_n (ordered-instance index for output slot s)
//  [900]      nkeep
//  [1024..11023]  dense pair-overlap table ovl[i*100+j] (i<j), zeroed by k_mask
//  [11264..]  bit-packed masks, stride 3648 words (12 x 304 rows), word col
//             aligned to GLOBAL word grid (word = x/32) so AND needs no shift.
#define OFF_ORDER 0
#define OFF_CLS   100
#define OFF_BOX   200
#define OFF_MSUM  600
#define OFF_SLOT  800
#define OFF_NK    900
#define OFF_OVL   1024
#define OFF_MASK  11264
#define ROWW      12
#define MSTRIDE   (ROWW * 304)

// Blocks [0,100): rank (redundant, from LDS) + rasterize bit-masks + msum.
// Also zero the ovl table (block b zeroes entries [b*100, b*100+100)).
__global__ __launch_bounds__(256) void k_mask(const float* __restrict__ mask_prob,
                                              const float* __restrict__ cls_prob,
                                              const float* __restrict__ rois,
                                              const int* __restrict__ cls_idx,
                                              int* __restrict__ ws) {
    int b = blockIdx.x, tid = threadIdx.x;
    __shared__ float s_p[NINST];
    __shared__ int s_order[NINST];
    __shared__ float lg[LOGSZ];
    __shared__ int red[256];
    if (tid < NINST) {
        s_p[tid] = cls_prob[tid];
        ws[OFF_OVL + b * NINST + tid] = 0; // zero ovl row b
    }
    __syncthreads();
    if (tid < NINST) {
        float p = s_p[tid];
        int r = 0;
        for (int j = 0; j < NINST; j++) {
            float q = s_p[j];
            r += (q > p) || (q == p && j < tid); // stable argsort(-cls_prob)
        }
        s_order[r] = tid;
    }
    __syncthreads();
    int n = b;
    int orig = s_order[n];
    int x0 = (int)rois[4 * orig], y0 = (int)rois[4 * orig + 1];
    int x1 = (int)rois[4 * orig + 2], y1 = (int)rois[4 * orig + 3];
    if (b == 0 && tid < NINST) { // publish metadata
        int o = s_order[tid];
        ws[OFF_ORDER + tid] = o;
        ws[OFF_CLS + tid] = cls_idx[o] - 1;
#pragma unroll
        for (int k = 0; k < 4; k++)
            ws[OFF_BOX + 4 * tid + k] = (int)rois[4 * o + k]; // trunc == astype(int32)
    }
    for (int i = tid; i < LOGSZ; i += 256) lg[i] = mask_prob[orig * LOGSZ + i];
    __syncthreads();
    int xs = max(x0, 0), xe = min(x1 + 1, IMG);
    int ys = max(y0, 0), ye = min(y1 + 1, IMG);
    int wx0 = xs >> 5, nw = ((xe + 31) >> 5) - wx0, nrows = ye - ys;
    float wf = fmaxf((float)(x1 - x0 + 1), 1.f), hf = fmaxf((float)(y1 - y0 + 1), 1.f);
    float rx = 28.f / wf, ry = 28.f / hf;
    unsigned* mb = (unsigned*)(ws + OFF_MASK) + n * MSTRIDE;
    int total = nrows * nw, cnt = 0;
    for (int t = tid; t < total; t += 256) {
        int row = t / nw, wc = t - row * nw;
        int y = ys + row;
        float sy = ((float)y - (float)y0 + 0.5f) * ry - 0.5f;
        sy = fminf(fmaxf(sy, 0.f), 27.f);
        int iy0 = (int)sy, iy1 = min(iy0 + 1, 27);
        float fy = sy - (float)iy0;
        const float* r0 = lg + iy0 * MLOG;
        const float* r1 = lg + iy1 * MLOG;
        unsigned bits = 0u;
        int xbase = (wx0 + wc) << 5;
        int j0 = max(xs - xbase, 0), j1 = min(xe - xbase, 32);
        for (int j = j0; j < j1; j++) {
            int xx = xbase + j;
            float sx = ((float)xx - (float)x0 + 0.5f) * rx - 0.5f;
            sx = fminf(fmaxf(sx, 0.f), 27.f);
            int ix0 = (int)sx, ix1 = min(ix0 + 1, 27);
            float fx = sx - (float)ix0;
            float val = (1.f - fy) * ((1.f - fx) * r0[ix0] + fx * r0[ix1]) +
                        fy * ((1.f - fx) * r1[ix0] + fx * r1[ix1]);
            bits |= (val > 0.f) ? (1u << j) : 0u;
        }
        mb[row * ROWW + wc] = bits;
        cnt += __popc(bits);
    }
    red[tid] = cnt;
    __syncthreads();
    for (int s = 128; s; s >>= 1) {
        if (tid < s) red[tid] += red[tid + s];
        __syncthreads();
    }
    if (tid == 0) ws[OFF_MSUM + n] = red[0];
}

// One wave per (i,j), i<j: same class, both non-empty, boxes overlap ->
// popcount(mask_i & mask_j) written straight into the dense ovl table.
__global__ __launch_bounds__(64) void k_pairs(int* __restrict__ ws) {
    int i = blockIdx.x, j = blockIdx.y, tid = threadIdx.x;
    if (i >= j) return;
    if (ws[OFF_CLS + i] != ws[OFF_CLS + j]) return;
    if (ws[OFF_MSUM + i] == 0 || ws[OFF_MSUM + j] == 0) return;
    const int* bi = ws + OFF_BOX + 4 * i;
    const int* bj = ws + OFF_BOX + 4 * j;
    int ixs = max(bi[0], 0), ixe = min(bi[2] + 1, IMG);
    int iys = max(bi[1], 0), iye = min(bi[3] + 1, IMG);
    int jxs = max(bj[0], 0), jxe = min(bj[2] + 1, IMG);
    int jys = max(bj[1], 0), jye = min(bj[3] + 1, IMG);
    if (!(ixs < jxe && jxs < ixe && iys < jye && jys < iye)) return;
    int iwx0 = ixs >> 5, jwx0 = jxs >> 5;
    int wlo = max(iwx0, jwx0);
    int whi = min((ixe + 31) >> 5, (jxe + 31) >> 5);
    int rlo = max(iys, jys), rhi = min(iye, jye);
    int nw = whi - wlo, nrows = rhi - rlo;
    const unsigned* mi = (const unsigned*)(ws + OFF_MASK) + i * MSTRIDE;
    const unsigned* mj = (const unsigned*)(ws + OFF_MASK) + j * MSTRIDE;
    int total = nrows * nw, cnt = 0;
    for (int t = tid; t < total; t += 64) {
        int row = t / nw, wc = t - row * nw;
        int y = rlo + row, w = wlo + wc;
        cnt += __popc(mi[(y - iys) * ROWW + (w - iwx0)] &
                      mj[(y - jys) * ROWW + (w - jwx0)]);
    }
    for (int off = 32; off; off >>= 1) cnt += __shfl_down(cnt, off);
    if (tid == 0) ws[OFF_OVL + i * NINST + j] = cnt;
}

// Single block: sequential keep scan. Per-step union bounded by
// max_pair <= |union| <= sum_pair (ints exact in float -> decided exactly
// when bounds agree; nc==1 is always exact). O(1) ovl lookup from the dense
// LDS table. Rare ambiguous case falls back to block-parallel union popcount.
__global__ __launch_bounds__(256) void k_scan(int* __restrict__ ws, float* __restrict__ out) {
    int tid = threadIdx.x;
    __shared__ int s_ovl[NINST * NINST]; // 40 KB
    __shared__ int s_box[4 * NINST];
    __shared__ int s_cls[NINST];
    __shared__ int s_msum[NINST];
    __shared__ int s_keep[NINST];
    __shared__ int s_cand[NINST];
    __shared__ int s_ncand, s_sum, s_max, s_need;
    __shared__ int red[256];
    for (int i = tid; i < NINST * NINST; i += 256) s_ovl[i] = ws[OFF_OVL + i];
    for (int i = tid; i < NINST; i += 256) {
        s_cls[i] = ws[OFF_CLS + i];
        s_msum[i] = ws[OFF_MSUM + i];
    }
    for (int i = tid; i < 4 * NINST; i += 256) s_box[i] = ws[OFF_BOX + i];
    const unsigned* maskbase = (const unsigned*)(ws + OFF_MASK);
    __syncthreads();

    for (int n = 0; n < NINST; n++) {
        if (tid == 0) { s_ncand = 0; s_sum = 0; s_max = 0; }
        __syncthreads(); // also publishes s_keep[n-1]
        if (tid < n && s_cls[tid] == s_cls[n] && s_keep[tid]) {
            int axs = max(s_box[4 * tid], 0), axe = min(s_box[4 * tid + 2] + 1, IMG);
            int ays = max(s_box[4 * tid + 1], 0), aye = min(s_box[4 * tid + 3] + 1, IMG);
            int nxs = max(s_box[4 * n], 0), nxe = min(s_box[4 * n + 2] + 1, IMG);
            int nys = max(s_box[4 * n + 1], 0), nye = min(s_box[4 * n + 3] + 1, IMG);
            if (axs < nxe && nxs < axe && ays < nye && nys < aye) {
                int k = atomicAdd(&s_ncand, 1);
                s_cand[k] = tid;
                int ovl = s_ovl[tid * NINST + n]; // O(1) lookup
                atomicAdd(&s_sum, ovl);
                atomicMax(&s_max, ovl);
            }
        }
        __syncthreads();
        if (tid == 0) {
            int msum = s_msum[n];
            float t = 0.3f * (float)msum;
            int keep = 0, need = 0;
            if (s_ncand == 0) keep = (msum > 0);
            else if ((float)s_sum <= t) keep = (msum > 0);
            else if ((float)s_max > t) keep = 0;
            else need = 1; // max <= t < sum (only possible with >=2 candidates)
            s_keep[n] = keep;
            s_need = need;
        }
        __syncthreads();
        if (s_need) { // exact union popcount, block-parallel
            int nc = s_ncand;
            int nxs = max(s_box[4 * n], 0), nxe = min(s_box[4 * n + 2] + 1, IMG);
            int nys = max(s_box[4 * n + 1], 0), nye = min(s_box[4 * n + 3] + 1, IMG);
            int wx0 = nxs >> 5, nw = ((nxe + 31) >> 5) - wx0, nrows = nye - nys;
            const unsigned* mn = maskbase + n * MSTRIDE;
            int total = nrows * nw, ovl = 0;
            for (int t2 = tid; t2 < total; t2 += 256) {
                int row = t2 / nw, wc = t2 - row * nw;
                unsigned bits = mn[row * ROWW + wc];
                if (!bits) continue;
                int y = nys + row, wa = wx0 + wc;
                unsigned img = 0;
                for (int k = 0; k < nc; k++) {
                    int m = s_cand[k];
                    int mys = max(s_box[4 * m + 1], 0), mye = min(s_box[4 * m + 3] + 1, IMG);
                    int mxs = max(s_box[4 * m], 0), mxe = min(s_box[4 * m + 2] + 1, IMG);
                    int mwx0 = mxs >> 5, mnw = ((mxe + 31) >> 5) - mwx0;
                    int rr = y - mys, cc = wa - mwx0;
                    if (rr >= 0 && rr < (mye - mys) && cc >= 0 && cc < mnw)
                        img |= maskbase[m * MSTRIDE + rr * ROWW + cc];
                }
                ovl += __popc(bits & img);
            }
            red[tid] = ovl;
            __syncthreads();
            for (int s = 128; s; s >>= 1) {
                if (tid < s) red[tid] += red[tid + s];
                __syncthreads();
            }
            if (tid == 0) {
                int msum = s_msum[n];
                s_keep[n] = (msum > 0) && ((float)red[0] <= 0.3f * (float)msum);
            }
            __syncthreads();
        }
    }
    __syncthreads();
    if (tid == 0) {
        int nk = 0;
        for (int n = 0; n < NINST; n++) {
            if (s_keep[n]) {
                ws[OFF_SLOT + nk] = n;
                out[nk] = (float)ws[OFF_ORDER + n];
                nk++;
            }
        }
        ws[OFF_NK] = nk;
        for (int s = nk; s < NINST; s++) out[s] = -1.f;
    }
}

// Full-image fused zero + energy write: every output element written exactly
// once, 256 MB total (strictly less traffic than zero-all + box rewrite).
__global__ __launch_bounds__(256) void k_out(const float* __restrict__ mask_prob,
                                             const int* __restrict__ ws,
                                             float* __restrict__ out) {
    int slot = blockIdx.y;
    int pi = blockIdx.x * 256 + threadIdx.x;
    int p = pi * 4;
    float4 res = make_float4(0.f, 0.f, 0.f, 0.f);
    int nk = ws[OFF_NK];
    if (slot < nk) {
        int n = ws[OFF_SLOT + slot];
        const int* box = ws + OFF_BOX;
        int x0 = box[4 * n], y0 = box[4 * n + 1], x1 = box[4 * n + 2], y1 = box[4 * n + 3];
        int xs = max(x0, 0), xe = min(x1 + 1, IMG);
        int ys = max(y0, 0), ye = min(y1 + 1, IMG);
        int y = p / IMG, x = p - y * IMG;
        if (y >= ys && y < ye && x + 3 >= xs && x < xe) {
            int orig = ws[OFF_ORDER + n];
            const float* lg = mask_prob + orig * LOGSZ;
            float wf = fmaxf((float)(x1 - x0 + 1), 1.f), hf = fmaxf((float)(y1 - y0 + 1), 1.f);
            float rx = 28.f / wf, ry = 28.f / hf;
            float sy = ((float)y - (float)y0 + 0.5f) * ry - 0.5f;
            sy = fminf(fmaxf(sy, 0.f), 27.f);
            int iy0 = (int)sy, iy1 = min(iy0 + 1, 27);
            float fy = sy - (float)iy0;
            const float* r0 = lg + iy0 * MLOG;
            const float* r1 = lg + iy1 * MLOG;
            float v[4];
#pragma unroll
            for (int j = 0; j < 4; j++) {
                int xx = x + j;
                float val = 0.f;
                if (xx >= xs && xx < xe) {
                    float sx = ((float)xx - (float)x0 + 0.5f) * rx - 0.5f;
                    sx = fminf(fmaxf(sx, 0.f), 27.f);
                    int ix0 = (int)sx, ix1 = min(ix0 + 1, 27);
                    float fx = sx - (float)ix0;
                    val = (1.f - fy) * ((1.f - fx) * r0[ix0] + fx * r0[ix1]) +
                          fy * ((1.f - fx) * r1[ix0] + fx * r1[ix1]);
                }
                v[j] = val;
            }
            res = make_float4(v[0], v[1], v[2], v[3]);
        }
    }
    float4* dst = ((float4*)(out + NINST)) + (size_t)slot * (IMG * IMG / 4) + pi;
    *dst = res;
}

extern "C" void kernel_launch(void* const* d_in, const int* in_sizes, int n_in,
                              void* d_out, int out_size, void* d_ws, size_t ws_size,
                              hipStream_t stream) {
    const float* rois      = (const float*)d_in[0];
    const float* cls_prob  = (const float*)d_in[1];
    const float* mask_prob = (const float*)d_in[2];
    const int*   cls_idx   = (const int*)d_in[3];
    int* ws = (int*)d_ws;
    float* out = (float*)d_out;

    k_mask<<<dim3(NINST), dim3(256), 0, stream>>>(mask_prob, cls_prob, rois, cls_idx, ws);
    k_pairs<<<dim3(NINST, NINST), dim3(64), 0, stream>>>(ws);
    k_scan<<<dim3(1), dim3(256), 0, stream>>>(ws, out);
    // 625 blocks x 256 thr x 4 floats = exactly 640000 px per slot
    k_out<<<dim3(IMG * IMG / 1024, NINST), dim3(256), 0, stream>>>(mask_prob, ws, out);
}